// Round 16
// baseline (90.363 us; speedup 1.0000x reference)
//
#include <hip/hip_runtime.h>
#include <hip/hip_bf16.h>
#include <math.h>

typedef __attribute__((ext_vector_type(4))) float f32x4;
typedef __attribute__((ext_vector_type(4))) int int4v;

#define NBINS 1000

// direct global -> LDS async copy, 16B per lane; LDS dest = wave-uniform base
__device__ __forceinline__ void gl16(const void* g, void* l) {
  __builtin_amdgcn_global_load_lds(
      (const __attribute__((address_space(1))) unsigned int*)g,
      (__attribute__((address_space(3))) unsigned int*)l, 16, 0, 0);
}

// decode OCP e4m3fn byte -> |value|, branch-light bit construction:
// e>0: (1+m/8)*2^(e-7) -> bits ((e+120)<<23)|(m<<20); e==0: m*2^-9.
__device__ __forceinline__ float fp8mag(unsigned b) {
  const unsigned e = (b >> 3) & 15u;
  const unsigned m = b & 7u;
  union { unsigned u; float f; } c;
  c.u = ((e + 120u) << 23) | (m << 20);
  return e ? c.f : (float)m * 0.001953125f;
}

// ---------------------------------------------------------------------------
// prep: quantize z to fp8 e4m3, PANEL-PACKED + SLOT-SWIZZLED image
// (identical layout to rounds 7/8/12). Row norms from the QUANTIZED values.
// ---------------------------------------------------------------------------
__global__ __launch_bounds__(256)
void prep_kernel(const float* __restrict__ za, const float* __restrict__ zb,
                 float* __restrict__ na, float* __restrict__ nb,
                 unsigned char* __restrict__ zpa, unsigned char* __restrict__ zpb,
                 int B, int D)
{
  const int row = blockIdx.x * 4 + (threadIdx.x >> 6);
  const int lane = threadIdx.x & 63;
  const float* src; float* dst; unsigned char* bd; int r;
  if (row < B) { src = za; dst = na; bd = zpa; r = row; }
  else         { src = zb; dst = nb; bd = zpb; r = row - B; }
  const int rr = r & 127;
  const int sw = (rr >> 1) & 3;
  const size_t tbase = (size_t)(r >> 7) * 128 * D;  // bytes
  float s = 0.f;
  for (int c = lane * 4; c < D; c += 256) {
    const f32x4 v = *(const f32x4*)&src[(size_t)r * D + c];
    unsigned u = (unsigned)__builtin_amdgcn_cvt_pk_fp8_f32(v[0], v[1], 0, false);
    u = (unsigned)__builtin_amdgcn_cvt_pk_fp8_f32(v[2], v[3], (int)u, true);
    const int sc = c >> 6;
    const int half = (c >> 5) & 1;
    const int kg = (c >> 3) & 3;
    const int rem = c & 7;  // 0 or 4
    const int slot = kg ^ sw;
    *(unsigned*)&bd[tbase + sc * 8192 + rr * 64 + slot * 16 + half * 8 + rem] = u;
    const float x0 = fp8mag(u & 255), x1 = fp8mag((u >> 8) & 255);
    const float x2 = fp8mag((u >> 16) & 255), x3 = fp8mag(u >> 24);
    s += x0 * x0 + x1 * x1 + x2 * x2 + x3 * x3;
  }
#pragma unroll
  for (int off = 32; off; off >>= 1) s += __shfl_xor(s, off);
  if (lane == 0) dst[r] = s;
}

// ---------------------------------------------------------------------------
// Merged kernel, 512-thread blocks, grid = 256 (1 block/CU):
//   blocks 0,1  : Efron Cox losses
//   blocks 2..255: persistent dcor blocks, 8-9 consecutive triangular tiles.
//   i-panels (full K=256) in REGISTERS; j staged to LDS in K=128 steps
//   (2 steps/tile, 32KB/step, dbuf 64KB, counted vmcnt(4), raw barriers).
// ---------------------------------------------------------------------------
__global__ __launch_bounds__(512, 2)
void dcor_kernel(const unsigned char* __restrict__ zpa,
                 const unsigned char* __restrict__ zpb,
                 const float* __restrict__ na, const float* __restrict__ nb,
                 float* __restrict__ Ra, float* __restrict__ Rb,
                 double* __restrict__ scalPart,
                 const float* __restrict__ r0, const int* __restrict__ e0, const int* __restrict__ t0,
                 const float* __restrict__ r1, const int* __restrict__ e1, const int* __restrict__ t1,
                 float* __restrict__ coxo,
                 int nt, int B, int D)
{
  __shared__ __align__(16) union SU {
    unsigned char jbuf[2][32768];  // [par][Aje 8K | Ajo 8K | Bje 8K | Bjo 8K]
    struct { float sS[NBINS], sT[NBINS], sDc[NBINS], sc0[NBINS], sc1[NBINS], red[16], red3[48]; } c;
  } u;

  const int tid = threadIdx.x;
  const int bid = blockIdx.x;

  if (bid < 2) {
    // ---------------- Cox path (512 threads) ----------------
    const float* risk = bid ? r1 : r0;
    const int* evt = bid ? e1 : e0;
    const int* tm  = bid ? t1 : t0;
    const int NT = 512;

    float m = -3.0e38f;
    for (int i = tid; i < B; i += NT) m = fmaxf(m, risk[i]);
#pragma unroll
    for (int off = 32; off; off >>= 1) m = fmaxf(m, __shfl_xor(m, off));
    if ((tid & 63) == 0) u.c.red[tid >> 6] = m;
    __syncthreads();
    if (tid == 0) {
      float mm = u.c.red[0];
      for (int wv = 1; wv < 8; ++wv) mm = fmaxf(mm, u.c.red[wv]);
      u.c.red[0] = mm;
    }
    __syncthreads();
    const float maxr = u.c.red[0];

    for (int i = tid; i < NBINS; i += NT) { u.c.sS[i] = 0.f; u.c.sT[i] = 0.f; u.c.sDc[i] = 0.f; }
    __syncthreads();

    float sr = 0.f, nev = 0.f;
    for (int i = tid; i < B; i += NT) {
      const float r = risk[i];
      int t = tm[i];
      t = t < 0 ? 0 : (t >= NBINS ? NBINS - 1 : t);
      const float ex = expf(r - maxr);
      atomicAdd(&u.c.sS[t], ex);
      if (evt[i]) {
        atomicAdd(&u.c.sT[t], ex);
        atomicAdd(&u.c.sDc[t], 1.0f);
        sr += r; nev += 1.0f;
      }
    }
    __syncthreads();

    for (int i = tid; i < NBINS; i += NT) u.c.sc0[i] = u.c.sS[i];
    __syncthreads();
    float* pin = u.c.sc0; float* pout = u.c.sc1;
    for (int off = 1; off < NBINS; off <<= 1) {
      for (int i = tid; i < NBINS; i += NT) {
        float v = pin[i];
        if (i + off < NBINS) v += pin[i + off];
        pout[i] = v;
      }
      __syncthreads();
      float* tmp = pin; pin = pout; pout = tmp;
    }

    float ls = 0.f;
    for (int t = tid; t < NBINS; t += NT) {
      const float d = u.c.sDc[t];
      if (d > 0.f) {
        const float tes = u.c.sT[t];
        const float rs = pin[t];
        for (float l = 0.f; l < d - 0.5f; l += 1.f)
          ls += logf(rs - (l / d) * tes + 1e-12f);
      }
    }

    float v1 = sr, v2 = nev, v3 = ls;
#pragma unroll
    for (int off = 32; off; off >>= 1) {
      v1 += __shfl_xor(v1, off); v2 += __shfl_xor(v2, off); v3 += __shfl_xor(v3, off);
    }
    if ((tid & 63) == 0) { int wv = tid >> 6; u.c.red3[wv] = v1; u.c.red3[16 + wv] = v2; u.c.red3[32 + wv] = v3; }
    __syncthreads();
    if (tid == 0) {
      float SR = 0.f, NEV = 0.f, LS = 0.f;
      for (int wv = 0; wv < 8; ++wv) { SR += u.c.red3[wv]; NEV += u.c.red3[16 + wv]; LS += u.c.red3[32 + wv]; }
      coxo[bid] = -(SR - LS - NEV * maxr) / (NEV + 1e-12f);
    }
    return;
  }

  // ---------------- dcor path ----------------
  const int lane = tid & 63;
  const int w = tid >> 6;  // 0..7
  const int p = bid - 2;   // 0..253

  // XCD-bijective banded block->q map (254 = 6*32 + 2*31)
  const int xcd = p & 7, pos = p >> 3;
  const int q = (xcd < 6 ? xcd * 32 : 192 + (xcd - 6) * 31) + pos;
  // 254 blocks: first 48 take 9 tiles, rest 8 (48*9 + 206*8 = 2080)
  const int start = (q < 48) ? 9 * q : 432 + 8 * (q - 48);
  const int cnt = (q < 48) ? 9 : 8;

  // decode start -> (ib0, jb0) in triangular order (jb >= ib)
  const double tn = (double)(2 * nt + 1);
  int ib0 = (int)((tn - sqrt(tn * tn - 8.0 * (double)start)) * 0.5);
  if (ib0 < 0) ib0 = 0;
  if (ib0 > nt - 1) ib0 = nt - 1;
  while (((ib0 + 1) * nt - ((ib0 + 1) * ib0) / 2) <= start) ++ib0;
  while ((ib0 * nt - (ib0 * (ib0 - 1)) / 2) > start) --ib0;
  const int jb0 = ib0 + (start - (ib0 * nt - (ib0 * (ib0 - 1)) / 2));

  // fragment geometry: wave = (wr 0..3 rows x32, wc 0..1 cols x64)
  const int wr = w >> 1, wc = w & 1;
  const int lrow = lane & 15;
  const int kg = lane >> 4;
  const int kgx = kg ^ ((lrow >> 1) & 3);   // inverts prep's slot swizzle
  const int abase = (wr * 32 + lrow) * 64 + kgx * 16;
  const int bbase = (wc * 64 + lrow) * 64 + kgx * 16;

  union I4L { int4v v; long l[2]; };

  int cib = ib0, cjb = jb0;        // compute tile
  int ssib = ib0, ssjb = jb0;      // stage tile (tile whose j is staged next)
  const unsigned char* pAi = zpa + (size_t)cib * 32768;
  const unsigned char* pBi = zpb + (size_t)cib * 32768;
  const unsigned char* sAj = zpa + (size_t)ssjb * 32768;
  const unsigned char* sBj = zpb + (size_t)ssjb * 32768;

  // i fragments (full K=256) in registers
  I4L iA[2][4], iB[2][4];
#pragma unroll
  for (int m2 = 0; m2 < 2; ++m2)
#pragma unroll
    for (int sc = 0; sc < 4; ++sc) {
      iA[m2][sc].v = *(const int4v*)(pAi + sc * 8192 + abase + m2 * 1024);
      iB[m2][sc].v = *(const int4v*)(pBi + sc * 8192 + abase + m2 * 1024);
    }

  const int lgofs = w * 1024 + lane * 16;  // per-lane offset within 8KB slice
  const int llofs = w * 1024;              // wave-uniform LDS dest offset

  // stage K=128 half-tile (sc pair scb, scb+1) of (sAj,sBj) into buffer par_
#define STAGE(par_, scb_) do {                                         \
    const size_t c0_ = (size_t)(scb_) * 8192 + lgofs;                  \
    const size_t c1_ = (size_t)((scb_) + 1) * 8192 + lgofs;            \
    gl16(sAj + c0_, &u.jbuf[par_][llofs]);                             \
    gl16(sAj + c1_, &u.jbuf[par_][8192 + llofs]);                      \
    gl16(sBj + c0_, &u.jbuf[par_][16384 + llofs]);                     \
    gl16(sBj + c1_, &u.jbuf[par_][24576 + llofs]);                     \
  } while (0)

  const f32x4 Z4 = {0.f, 0.f, 0.f, 0.f};
  f32x4 accA[2][4], accB[2][4];
#pragma unroll
  for (int m2 = 0; m2 < 2; ++m2)
#pragma unroll
    for (int n2 = 0; n2 < 4; ++n2) { accA[m2][n2] = Z4; accB[m2][n2] = Z4; }

  double dp0 = 0.0, dp1 = 0.0, dp2 = 0.0;  // per-wave scalar partials

  // prologue: stage tile0's two K=128 halves into buffers 0,1
  STAGE(0, 0);
  STAGE(1, 2);

  for (int t = 0; t < cnt; ++t) {
#pragma unroll
    for (int h = 0; h < 2; ++h) {   // step = 2t+h; buffer parity == h
      if (t == cnt - 1 && h == 1) asm volatile("s_waitcnt vmcnt(0)" ::: "memory");
      else                        asm volatile("s_waitcnt vmcnt(4)" ::: "memory");
      __builtin_amdgcn_sched_barrier(0);
      __builtin_amdgcn_s_barrier();
      __builtin_amdgcn_sched_barrier(0);

      // compute both sc halves (sc = 2h, 2h+1) from jbuf[h]
      {
        const unsigned char* jb_ = &u.jbuf[h][0];
#pragma unroll
        for (int half = 0; half < 2; ++half) {
          I4L bA[4], bB[4];
#pragma unroll
          for (int n2 = 0; n2 < 4; ++n2) bA[n2].v = *(const int4v*)&jb_[half * 8192 + bbase + n2 * 1024];
#pragma unroll
          for (int n2 = 0; n2 < 4; ++n2) bB[n2].v = *(const int4v*)&jb_[16384 + half * 8192 + bbase + n2 * 1024];
          __builtin_amdgcn_s_setprio(1);
#pragma unroll
          for (int m2 = 0; m2 < 2; ++m2)
#pragma unroll
            for (int n2 = 0; n2 < 4; ++n2) {
              accA[m2][n2] = __builtin_amdgcn_mfma_f32_16x16x32_fp8_fp8(iA[m2][2 * h + half].l[0], bA[n2].l[0], accA[m2][n2], 0, 0, 0);
              accA[m2][n2] = __builtin_amdgcn_mfma_f32_16x16x32_fp8_fp8(iA[m2][2 * h + half].l[1], bA[n2].l[1], accA[m2][n2], 0, 0, 0);
            }
#pragma unroll
          for (int m2 = 0; m2 < 2; ++m2)
#pragma unroll
            for (int n2 = 0; n2 < 4; ++n2) {
              accB[m2][n2] = __builtin_amdgcn_mfma_f32_16x16x32_fp8_fp8(iB[m2][2 * h + half].l[0], bB[n2].l[0], accB[m2][n2], 0, 0, 0);
              accB[m2][n2] = __builtin_amdgcn_mfma_f32_16x16x32_fp8_fp8(iB[m2][2 * h + half].l[1], bB[n2].l[1], accB[m2][n2], 0, 0, 0);
            }
          __builtin_amdgcn_s_setprio(0);
        }
      }

      __builtin_amdgcn_sched_barrier(0);
      __builtin_amdgcn_s_barrier();
      __builtin_amdgcn_sched_barrier(0);

      // issue stage for step s+2 (next tile, same h) into freed buffer h
      if (t + 1 < cnt) {
        if (h == 0) {  // advance stage tile once per tile
          if (++ssjb == nt) { ++ssib; ssjb = ssib; }
          sAj = zpa + (size_t)ssjb * 32768;
          sBj = zpb + (size_t)ssjb * 32768;
        }
        STAGE(h, 2 * h);
      }
    }

    // ---------------- epilogue for tile (cib,cjb) ----------------
    {
      const bool offd = (cjb != cib);
      const float fac = offd ? 2.0f : 1.0f;
      float pab = 0.f, paa = 0.f, pbb = 0.f;
      float rsa[2][4], rsb[2][4];
      float csa[4] = {0.f, 0.f, 0.f, 0.f}, csb[4] = {0.f, 0.f, 0.f, 0.f};
#pragma unroll
      for (int m2 = 0; m2 < 2; ++m2)
#pragma unroll
        for (int r = 0; r < 4; ++r) { rsa[m2][r] = 0.f; rsb[m2][r] = 0.f; }

      const int gi0 = cib * 128 + wr * 32;
      const int gj0 = cjb * 128 + wc * 64;

#pragma unroll
      for (int m2 = 0; m2 < 2; ++m2) {
        const int gr = gi0 + m2 * 16 + kg * 4;
        const f32x4 nai = *(const f32x4*)&na[gr];
        const f32x4 nbi = *(const f32x4*)&nb[gr];
#pragma unroll
        for (int n2 = 0; n2 < 4; ++n2) {
          const int gc = gj0 + n2 * 16 + lrow;
          const float naj = na[gc];
          const float nbj = nb[gc];
          const f32x4 ga = accA[m2][n2];
          const f32x4 gb = accB[m2][n2];
#pragma unroll
          for (int r = 0; r < 4; ++r) {
            const float d2a = fmaxf(nai[r] + naj - 2.0f * ga[r], 1e-8f);
            const float d2b = fmaxf(nbi[r] + nbj - 2.0f * gb[r], 1e-8f);
            const float Da = __builtin_amdgcn_sqrtf(d2a);
            const float Db = __builtin_amdgcn_sqrtf(d2b);
            pab += Da * Db;
            paa += d2a;
            pbb += d2b;
            rsa[m2][r] += Da;
            rsb[m2][r] += Db;
            csa[n2] += Da;
            csb[n2] += Db;
          }
        }
      }

#pragma unroll
      for (int m2 = 0; m2 < 2; ++m2)
#pragma unroll
        for (int r = 0; r < 4; ++r) {
          float va = rsa[m2][r], vb = rsb[m2][r];
          va += __shfl_xor(va, 1); va += __shfl_xor(va, 2); va += __shfl_xor(va, 4); va += __shfl_xor(va, 8);
          vb += __shfl_xor(vb, 1); vb += __shfl_xor(vb, 2); vb += __shfl_xor(vb, 4); vb += __shfl_xor(vb, 8);
          if (lrow == 0) {
            const int gi = gi0 + m2 * 16 + kg * 4 + r;
            atomicAdd(&Ra[gi], va);
            atomicAdd(&Rb[gi], vb);
          }
        }

      if (offd) {
#pragma unroll
        for (int n2 = 0; n2 < 4; ++n2) {
          float va = csa[n2], vb = csb[n2];
          va += __shfl_xor(va, 16); va += __shfl_xor(va, 32);
          vb += __shfl_xor(vb, 16); vb += __shfl_xor(vb, 32);
          if (kg == 0) {
            const int gj = gj0 + n2 * 16 + lrow;
            atomicAdd(&Ra[gj], va);
            atomicAdd(&Rb[gj], vb);
          }
        }
      }

      float q1 = fac * pab, q2 = fac * paa, q3 = fac * pbb;
#pragma unroll
      for (int off = 32; off; off >>= 1) {
        q1 += __shfl_xor(q1, off); q2 += __shfl_xor(q2, off); q3 += __shfl_xor(q3, off);
      }
      dp0 += (double)q1; dp1 += (double)q2; dp2 += (double)q3;
    }

    // advance compute tile; reload i fragments on band change
    const int oldib = cib;
    if (++cjb == nt) { ++cib; cjb = cib; }
    if (cib != oldib && t + 1 < cnt) {
      pAi = zpa + (size_t)cib * 32768;
      pBi = zpb + (size_t)cib * 32768;
#pragma unroll
      for (int m2 = 0; m2 < 2; ++m2)
#pragma unroll
        for (int sc = 0; sc < 4; ++sc) {
          iA[m2][sc].v = *(const int4v*)(pAi + sc * 8192 + abase + m2 * 1024);
          iB[m2][sc].v = *(const int4v*)(pBi + sc * 8192 + abase + m2 * 1024);
        }
    }
#pragma unroll
    for (int m2 = 0; m2 < 2; ++m2)
#pragma unroll
      for (int n2 = 0; n2 < 4; ++n2) { accA[m2][n2] = Z4; accB[m2][n2] = Z4; }
  }
#undef STAGE

  // one write per (block, wave): 254*8 slots of 3 doubles
  if (lane == 0) {
    double* sp = scalPart + (size_t)(p * 8 + w) * 3;
    sp[0] = dp0; sp[1] = dp1; sp[2] = dp2;
  }
}

// ---------------------------------------------------------------------------
// Final combine (fp64 to survive the ~4-decade cancellation in S terms).
// ---------------------------------------------------------------------------
__global__ __launch_bounds__(256)
void finalize_kernel(const float* __restrict__ Ra, const float* __restrict__ Rb,
                     const double* __restrict__ scalPart, int NS,
                     const float* __restrict__ coxo,
                     const float* __restrict__ iw, const float* __restrict__ ic,
                     float* __restrict__ out, int B)
{
  const int tid = threadIdx.x;
  double v[8];
#pragma unroll
  for (int k = 0; k < 8; ++k) v[k] = 0.0;
  for (int i = tid; i < B; i += 256) {
    const double a = Ra[i], b = Rb[i];
    v[0] += a; v[1] += b; v[2] += a * b; v[3] += a * a; v[4] += b * b;
  }
  for (int i = tid; i < NS; i += 256) {
    const double* sp = scalPart + (size_t)i * 3;
    v[5] += sp[0]; v[6] += sp[1]; v[7] += sp[2];
  }
#pragma unroll
  for (int k = 0; k < 8; ++k)
#pragma unroll
    for (int off = 32; off; off >>= 1) v[k] += __shfl_xor(v[k], off);
  __shared__ double sred[32];
  const int w = tid >> 6;
  if ((tid & 63) == 0) {
#pragma unroll
    for (int k = 0; k < 8; ++k) sred[k * 4 + w] = v[k];
  }
  __syncthreads();
  if (tid == 0) {
    double r[8];
#pragma unroll
    for (int k = 0; k < 8; ++k) r[k] = sred[k * 4] + sred[k * 4 + 1] + sred[k * 4 + 2] + sred[k * 4 + 3];
    const double ta = r[0], tb = r[1], sab = r[2], saa = r[3], sbb = r[4];
    const double Pab = r[5], Paa = r[6], Pbb = r[7];
    const double n = (double)B;
    const double Sab = Pab - (2.0 / n) * sab + ta * tb / (n * n);
    const double Saa = Paa - (2.0 / n) * saa + ta * ta / (n * n);
    const double Sbb = Pbb - (2.0 / n) * sbb + tb * tb / (n * n);
    const double dcov = Sab / (n * n);
    const double va = Saa / (n * n);
    const double vb = Sbb / (n * n);
    const double l_cca = 1.0 - dcov / sqrt(fmax(va * vb, 1e-8));
    const double total = (double)coxo[0] + (double)coxo[1]
                       + (0.1 * l_cca + 0.05 * ((double)iw[0] + (double)ic[0]));
    out[0] = (float)total;
  }
}

// ---------------------------------------------------------------------------
extern "C" void kernel_launch(void* const* d_in, const int* in_sizes, int n_in,
                              void* d_out, int out_size, void* d_ws, size_t ws_size,
                              hipStream_t stream)
{
  (void)n_in; (void)out_size; (void)ws_size;
  const float* risk_os   = (const float*)d_in[0];
  const float* risk_rfs  = (const float*)d_in[1];
  const float* z_ct      = (const float*)d_in[2];
  const float* z_wsi     = (const float*)d_in[3];
  const float* intra_wsi = (const float*)d_in[4];
  const float* intra_ct  = (const float*)d_in[5];
  const int* evt_os  = (const int*)d_in[6];
  const int* tm_os   = (const int*)d_in[7];
  const int* evt_rfs = (const int*)d_in[8];
  const int* tm_rfs  = (const int*)d_in[9];

  const int B = in_sizes[0];        // 8192
  const int D = in_sizes[2] / B;    // 256
  const int nt = B / 128;           // 64
  const int NS = 254 * 8;           // per-(block,wave) scalar slots

  // ws layout (float units):
  // Ra | Rb | coxo(16) | na | nb | scalPart (NS*3 doubles) | fp8 packed z
  float* ws = (float*)d_ws;
  float* Ra = ws;
  float* Rb = ws + B;
  float* coxo = ws + 2 * B;
  float* na  = ws + 2 * B + 16;
  float* nbv = ws + 3 * B + 16;
  double* scalPart = (double*)(ws + 4 * B + 16);
  unsigned char* zpa = (unsigned char*)(ws + 4 * B + 16 + 6 * NS + 8);
  unsigned char* zpb = zpa + (size_t)B * D;

  (void)hipMemsetAsync(d_ws, 0, (size_t)(2 * B) * sizeof(float), stream);

  prep_kernel<<<(2 * B) / 4, 256, 0, stream>>>(z_ct, z_wsi, na, nbv, zpa, zpb, B, D);
  dcor_kernel<<<256, 512, 0, stream>>>(zpa, zpb, na, nbv, Ra, Rb, scalPart,
                                       risk_os, evt_os, tm_os, risk_rfs, evt_rfs, tm_rfs,
                                       coxo, nt, B, D);
  finalize_kernel<<<1, 256, 0, stream>>>(Ra, Rb, scalPart, NS, coxo, intra_wsi, intra_ct, (float*)d_out, B);
}

// Round 17
// 85.480 us; speedup vs baseline: 1.0571x; 1.0571x over previous
//
#include <hip/hip_runtime.h>
#include <hip/hip_bf16.h>
#include <math.h>

typedef __attribute__((ext_vector_type(4))) float f32x4;
typedef __attribute__((ext_vector_type(4))) int int4v;

#define NBINS 1000
// sched_barrier mask: allow ALU|VALU|SALU|MFMA to cross; pin DS + VMEM.
#define SBAR_MASK 0xF

// direct global -> LDS async copy, 16B per lane; LDS dest = wave-uniform base
__device__ __forceinline__ void gl16(const void* g, void* l) {
  __builtin_amdgcn_global_load_lds(
      (const __attribute__((address_space(1))) unsigned int*)g,
      (__attribute__((address_space(3))) unsigned int*)l, 16, 0, 0);
}

// decode OCP e4m3fn byte -> |value|, branch-light bit construction
__device__ __forceinline__ float fp8mag(unsigned b) {
  const unsigned e = (b >> 3) & 15u;
  const unsigned m = b & 7u;
  union { unsigned u; float f; } c;
  c.u = ((e + 120u) << 23) | (m << 20);
  return e ? c.f : (float)m * 0.001953125f;
}

// ---------------------------------------------------------------------------
// prep: quantize z to fp8 e4m3, PANEL-PACKED + SLOT-SWIZZLED image
// (identical layout to rounds 7/8/12). Row norms from the QUANTIZED values.
// Also zeroes Ra/Rb (replaces the memset dispatch).
// ---------------------------------------------------------------------------
__global__ __launch_bounds__(256)
void prep_kernel(const float* __restrict__ za, const float* __restrict__ zb,
                 float* __restrict__ na, float* __restrict__ nb,
                 unsigned char* __restrict__ zpa, unsigned char* __restrict__ zpb,
                 float* __restrict__ Ra, float* __restrict__ Rb,
                 int B, int D)
{
  const int row = blockIdx.x * 4 + (threadIdx.x >> 6);
  const int lane = threadIdx.x & 63;
  const float* src; float* dst; unsigned char* bd; int r;
  if (row < B) { src = za; dst = na; bd = zpa; r = row; }
  else         { src = zb; dst = nb; bd = zpb; r = row - B; }
  if (row < B && lane == 0) { Ra[r] = 0.f; Rb[r] = 0.f; }
  const int rr = r & 127;
  const int sw = (rr >> 1) & 3;
  const size_t tbase = (size_t)(r >> 7) * 128 * D;  // bytes
  float s = 0.f;
  for (int c = lane * 4; c < D; c += 256) {
    const f32x4 v = *(const f32x4*)&src[(size_t)r * D + c];
    unsigned u = (unsigned)__builtin_amdgcn_cvt_pk_fp8_f32(v[0], v[1], 0, false);
    u = (unsigned)__builtin_amdgcn_cvt_pk_fp8_f32(v[2], v[3], (int)u, true);
    const int sc = c >> 6;
    const int half = (c >> 5) & 1;
    const int kg = (c >> 3) & 3;
    const int rem = c & 7;  // 0 or 4
    const int slot = kg ^ sw;
    *(unsigned*)&bd[tbase + sc * 8192 + rr * 64 + slot * 16 + half * 8 + rem] = u;
    const float x0 = fp8mag(u & 255), x1 = fp8mag((u >> 8) & 255);
    const float x2 = fp8mag((u >> 16) & 255), x3 = fp8mag(u >> 24);
    s += x0 * x0 + x1 * x1 + x2 * x2 + x3 * x3;
  }
#pragma unroll
  for (int off = 32; off; off >>= 1) s += __shfl_xor(s, off);
  if (lane == 0) dst[r] = s;
}

// ---------------------------------------------------------------------------
// Merged kernel, 512-thread blocks, grid = 256 (1 block/CU):
//   blocks 0,1  : Efron Cox losses
//   blocks 2..255: persistent dcor blocks, 8-9 consecutive triangular tiles.
//   i-panels (full K=256) in REGISTERS; j staged to LDS in K=128 steps
//   (2 steps/tile, 32KB/step, dbuf 64KB, counted vmcnt(4), raw barriers).
//   sched_barrier(0xF): VALU/MFMA may migrate across barrier fences
//   (epilogue fills wait shadows); DS+VMEM pinned for correctness.
// ---------------------------------------------------------------------------
__global__ __launch_bounds__(512, 2)
void dcor_kernel(const unsigned char* __restrict__ zpa,
                 const unsigned char* __restrict__ zpb,
                 const float* __restrict__ na, const float* __restrict__ nb,
                 float* __restrict__ Ra, float* __restrict__ Rb,
                 double* __restrict__ scalPart,
                 const float* __restrict__ r0, const int* __restrict__ e0, const int* __restrict__ t0,
                 const float* __restrict__ r1, const int* __restrict__ e1, const int* __restrict__ t1,
                 float* __restrict__ coxo,
                 int nt, int B, int D)
{
  __shared__ __align__(16) union SU {
    unsigned char jbuf[2][32768];  // [par][Aje 8K | Ajo 8K | Bje 8K | Bjo 8K]
    struct { float sS[NBINS], sT[NBINS], sDc[NBINS], sc0[NBINS], sc1[NBINS], red[16], red3[48]; } c;
  } u;

  const int tid = threadIdx.x;
  const int bid = blockIdx.x;

  if (bid < 2) {
    // ---------------- Cox path (512 threads) ----------------
    const float* risk = bid ? r1 : r0;
    const int* evt = bid ? e1 : e0;
    const int* tm  = bid ? t1 : t0;
    const int NT = 512;

    float m = -3.0e38f;
    for (int i = tid; i < B; i += NT) m = fmaxf(m, risk[i]);
#pragma unroll
    for (int off = 32; off; off >>= 1) m = fmaxf(m, __shfl_xor(m, off));
    if ((tid & 63) == 0) u.c.red[tid >> 6] = m;
    __syncthreads();
    if (tid == 0) {
      float mm = u.c.red[0];
      for (int wv = 1; wv < 8; ++wv) mm = fmaxf(mm, u.c.red[wv]);
      u.c.red[0] = mm;
    }
    __syncthreads();
    const float maxr = u.c.red[0];

    for (int i = tid; i < NBINS; i += NT) { u.c.sS[i] = 0.f; u.c.sT[i] = 0.f; u.c.sDc[i] = 0.f; }
    __syncthreads();

    float sr = 0.f, nev = 0.f;
    for (int i = tid; i < B; i += NT) {
      const float r = risk[i];
      int t = tm[i];
      t = t < 0 ? 0 : (t >= NBINS ? NBINS - 1 : t);
      const float ex = expf(r - maxr);
      atomicAdd(&u.c.sS[t], ex);
      if (evt[i]) {
        atomicAdd(&u.c.sT[t], ex);
        atomicAdd(&u.c.sDc[t], 1.0f);
        sr += r; nev += 1.0f;
      }
    }
    __syncthreads();

    for (int i = tid; i < NBINS; i += NT) u.c.sc0[i] = u.c.sS[i];
    __syncthreads();
    float* pin = u.c.sc0; float* pout = u.c.sc1;
    for (int off = 1; off < NBINS; off <<= 1) {
      for (int i = tid; i < NBINS; i += NT) {
        float v = pin[i];
        if (i + off < NBINS) v += pin[i + off];
        pout[i] = v;
      }
      __syncthreads();
      float* tmp = pin; pin = pout; pout = tmp;
    }

    float ls = 0.f;
    for (int t = tid; t < NBINS; t += NT) {
      const float d = u.c.sDc[t];
      if (d > 0.f) {
        const float tes = u.c.sT[t];
        const float rs = pin[t];
        for (float l = 0.f; l < d - 0.5f; l += 1.f)
          ls += logf(rs - (l / d) * tes + 1e-12f);
      }
    }

    float v1 = sr, v2 = nev, v3 = ls;
#pragma unroll
    for (int off = 32; off; off >>= 1) {
      v1 += __shfl_xor(v1, off); v2 += __shfl_xor(v2, off); v3 += __shfl_xor(v3, off);
    }
    if ((tid & 63) == 0) { int wv = tid >> 6; u.c.red3[wv] = v1; u.c.red3[16 + wv] = v2; u.c.red3[32 + wv] = v3; }
    __syncthreads();
    if (tid == 0) {
      float SR = 0.f, NEV = 0.f, LS = 0.f;
      for (int wv = 0; wv < 8; ++wv) { SR += u.c.red3[wv]; NEV += u.c.red3[16 + wv]; LS += u.c.red3[32 + wv]; }
      coxo[bid] = -(SR - LS - NEV * maxr) / (NEV + 1e-12f);
    }
    return;
  }

  // ---------------- dcor path ----------------
  const int lane = tid & 63;
  const int w = tid >> 6;  // 0..7
  const int p = bid - 2;   // 0..253

  // XCD-bijective banded block->q map (254 = 6*32 + 2*31)
  const int xcd = p & 7, pos = p >> 3;
  const int q = (xcd < 6 ? xcd * 32 : 192 + (xcd - 6) * 31) + pos;
  // 254 blocks: first 48 take 9 tiles, rest 8 (48*9 + 206*8 = 2080)
  const int start = (q < 48) ? 9 * q : 432 + 8 * (q - 48);
  const int cnt = (q < 48) ? 9 : 8;

  // decode start -> (ib0, jb0) in triangular order (jb >= ib)
  const double tn = (double)(2 * nt + 1);
  int ib0 = (int)((tn - sqrt(tn * tn - 8.0 * (double)start)) * 0.5);
  if (ib0 < 0) ib0 = 0;
  if (ib0 > nt - 1) ib0 = nt - 1;
  while (((ib0 + 1) * nt - ((ib0 + 1) * ib0) / 2) <= start) ++ib0;
  while ((ib0 * nt - (ib0 * (ib0 - 1)) / 2) > start) --ib0;
  const int jb0 = ib0 + (start - (ib0 * nt - (ib0 * (ib0 - 1)) / 2));

  // fragment geometry: wave = (wr 0..3 rows x32, wc 0..1 cols x64)
  const int wr = w >> 1, wc = w & 1;
  const int lrow = lane & 15;
  const int kg = lane >> 4;
  const int kgx = kg ^ ((lrow >> 1) & 3);   // inverts prep's slot swizzle
  const int abase = (wr * 32 + lrow) * 64 + kgx * 16;
  const int bbase = (wc * 64 + lrow) * 64 + kgx * 16;

  union I4L { int4v v; long l[2]; };

  int cib = ib0, cjb = jb0;        // compute tile
  int ssib = ib0, ssjb = jb0;      // stage tile (tile whose j is staged next)
  const unsigned char* pAi = zpa + (size_t)cib * 32768;
  const unsigned char* pBi = zpb + (size_t)cib * 32768;
  const unsigned char* sAj = zpa + (size_t)ssjb * 32768;
  const unsigned char* sBj = zpb + (size_t)ssjb * 32768;

  // i fragments (full K=256) in registers
  I4L iA[2][4], iB[2][4];
#pragma unroll
  for (int m2 = 0; m2 < 2; ++m2)
#pragma unroll
    for (int sc = 0; sc < 4; ++sc) {
      iA[m2][sc].v = *(const int4v*)(pAi + sc * 8192 + abase + m2 * 1024);
      iB[m2][sc].v = *(const int4v*)(pBi + sc * 8192 + abase + m2 * 1024);
    }

  const int lgofs = w * 1024 + lane * 16;  // per-lane offset within 8KB slice
  const int llofs = w * 1024;              // wave-uniform LDS dest offset

  // stage K=128 half-tile (sc pair scb, scb+1) of (sAj,sBj) into buffer par_
#define STAGE(par_, scb_) do {                                         \
    const size_t c0_ = (size_t)(scb_) * 8192 + lgofs;                  \
    const size_t c1_ = (size_t)((scb_) + 1) * 8192 + lgofs;            \
    gl16(sAj + c0_, &u.jbuf[par_][llofs]);                             \
    gl16(sAj + c1_, &u.jbuf[par_][8192 + llofs]);                      \
    gl16(sBj + c0_, &u.jbuf[par_][16384 + llofs]);                     \
    gl16(sBj + c1_, &u.jbuf[par_][24576 + llofs]);                     \
  } while (0)

  const f32x4 Z4 = {0.f, 0.f, 0.f, 0.f};
  f32x4 accA[2][4], accB[2][4];
#pragma unroll
  for (int m2 = 0; m2 < 2; ++m2)
#pragma unroll
    for (int n2 = 0; n2 < 4; ++n2) { accA[m2][n2] = Z4; accB[m2][n2] = Z4; }

  double dp0 = 0.0, dp1 = 0.0, dp2 = 0.0;  // per-wave scalar partials

  // prologue: stage tile0's two K=128 halves into buffers 0,1
  STAGE(0, 0);
  STAGE(1, 2);

  for (int t = 0; t < cnt; ++t) {
#pragma unroll
    for (int h = 0; h < 2; ++h) {   // step = 2t+h; buffer parity == h
      if (t == cnt - 1 && h == 1) asm volatile("s_waitcnt vmcnt(0)" ::: "memory");
      else                        asm volatile("s_waitcnt vmcnt(4)" ::: "memory");
      __builtin_amdgcn_sched_barrier(SBAR_MASK);
      __builtin_amdgcn_s_barrier();
      __builtin_amdgcn_sched_barrier(SBAR_MASK);

      // compute both sc halves (sc = 2h, 2h+1) from jbuf[h]
      {
        const unsigned char* jb_ = &u.jbuf[h][0];
#pragma unroll
        for (int half = 0; half < 2; ++half) {
          I4L bA[4], bB[4];
#pragma unroll
          for (int n2 = 0; n2 < 4; ++n2) bA[n2].v = *(const int4v*)&jb_[half * 8192 + bbase + n2 * 1024];
#pragma unroll
          for (int n2 = 0; n2 < 4; ++n2) bB[n2].v = *(const int4v*)&jb_[16384 + half * 8192 + bbase + n2 * 1024];
          __builtin_amdgcn_s_setprio(1);
#pragma unroll
          for (int m2 = 0; m2 < 2; ++m2)
#pragma unroll
            for (int n2 = 0; n2 < 4; ++n2) {
              accA[m2][n2] = __builtin_amdgcn_mfma_f32_16x16x32_fp8_fp8(iA[m2][2 * h + half].l[0], bA[n2].l[0], accA[m2][n2], 0, 0, 0);
              accA[m2][n2] = __builtin_amdgcn_mfma_f32_16x16x32_fp8_fp8(iA[m2][2 * h + half].l[1], bA[n2].l[1], accA[m2][n2], 0, 0, 0);
            }
#pragma unroll
          for (int m2 = 0; m2 < 2; ++m2)
#pragma unroll
            for (int n2 = 0; n2 < 4; ++n2) {
              accB[m2][n2] = __builtin_amdgcn_mfma_f32_16x16x32_fp8_fp8(iB[m2][2 * h + half].l[0], bB[n2].l[0], accB[m2][n2], 0, 0, 0);
              accB[m2][n2] = __builtin_amdgcn_mfma_f32_16x16x32_fp8_fp8(iB[m2][2 * h + half].l[1], bB[n2].l[1], accB[m2][n2], 0, 0, 0);
            }
          __builtin_amdgcn_s_setprio(0);
        }
      }

      __builtin_amdgcn_sched_barrier(SBAR_MASK);
      __builtin_amdgcn_s_barrier();
      __builtin_amdgcn_sched_barrier(SBAR_MASK);

      // issue stage for step s+2 (next tile, same h) into freed buffer h
      if (t + 1 < cnt) {
        if (h == 0) {  // advance stage tile once per tile
          if (++ssjb == nt) { ++ssib; ssjb = ssib; }
          sAj = zpa + (size_t)ssjb * 32768;
          sBj = zpb + (size_t)ssjb * 32768;
        }
        STAGE(h, 2 * h);
      }
    }

    // ---------------- epilogue for tile (cib,cjb) ----------------
    {
      const bool offd = (cjb != cib);
      const float fac = offd ? 2.0f : 1.0f;
      float pab = 0.f, paa = 0.f, pbb = 0.f;
      float rsa[2][4], rsb[2][4];
      float csa[4] = {0.f, 0.f, 0.f, 0.f}, csb[4] = {0.f, 0.f, 0.f, 0.f};
#pragma unroll
      for (int m2 = 0; m2 < 2; ++m2)
#pragma unroll
        for (int r = 0; r < 4; ++r) { rsa[m2][r] = 0.f; rsb[m2][r] = 0.f; }

      const int gi0 = cib * 128 + wr * 32;
      const int gj0 = cjb * 128 + wc * 64;

#pragma unroll
      for (int m2 = 0; m2 < 2; ++m2) {
        const int gr = gi0 + m2 * 16 + kg * 4;
        const f32x4 nai = *(const f32x4*)&na[gr];
        const f32x4 nbi = *(const f32x4*)&nb[gr];
#pragma unroll
        for (int n2 = 0; n2 < 4; ++n2) {
          const int gc = gj0 + n2 * 16 + lrow;
          const float naj = na[gc];
          const float nbj = nb[gc];
          const f32x4 ga = accA[m2][n2];
          const f32x4 gb = accB[m2][n2];
#pragma unroll
          for (int r = 0; r < 4; ++r) {
            const float d2a = fmaxf(nai[r] + naj - 2.0f * ga[r], 1e-8f);
            const float d2b = fmaxf(nbi[r] + nbj - 2.0f * gb[r], 1e-8f);
            const float Da = __builtin_amdgcn_sqrtf(d2a);
            const float Db = __builtin_amdgcn_sqrtf(d2b);
            pab += Da * Db;
            paa += d2a;
            pbb += d2b;
            rsa[m2][r] += Da;
            rsb[m2][r] += Db;
            csa[n2] += Da;
            csb[n2] += Db;
          }
        }
      }

#pragma unroll
      for (int m2 = 0; m2 < 2; ++m2)
#pragma unroll
        for (int r = 0; r < 4; ++r) {
          float va = rsa[m2][r], vb = rsb[m2][r];
          va += __shfl_xor(va, 1); va += __shfl_xor(va, 2); va += __shfl_xor(va, 4); va += __shfl_xor(va, 8);
          vb += __shfl_xor(vb, 1); vb += __shfl_xor(vb, 2); vb += __shfl_xor(vb, 4); vb += __shfl_xor(vb, 8);
          if (lrow == 0) {
            const int gi = gi0 + m2 * 16 + kg * 4 + r;
            atomicAdd(&Ra[gi], va);
            atomicAdd(&Rb[gi], vb);
          }
        }

      if (offd) {
#pragma unroll
        for (int n2 = 0; n2 < 4; ++n2) {
          float va = csa[n2], vb = csb[n2];
          va += __shfl_xor(va, 16); va += __shfl_xor(va, 32);
          vb += __shfl_xor(vb, 16); vb += __shfl_xor(vb, 32);
          if (kg == 0) {
            const int gj = gj0 + n2 * 16 + lrow;
            atomicAdd(&Ra[gj], va);
            atomicAdd(&Rb[gj], vb);
          }
        }
      }

      float q1 = fac * pab, q2 = fac * paa, q3 = fac * pbb;
#pragma unroll
      for (int off = 32; off; off >>= 1) {
        q1 += __shfl_xor(q1, off); q2 += __shfl_xor(q2, off); q3 += __shfl_xor(q3, off);
      }
      dp0 += (double)q1; dp1 += (double)q2; dp2 += (double)q3;
    }

    // advance compute tile; reload i fragments on band change
    const int oldib = cib;
    if (++cjb == nt) { ++cib; cjb = cib; }
    if (cib != oldib && t + 1 < cnt) {
      pAi = zpa + (size_t)cib * 32768;
      pBi = zpb + (size_t)cib * 32768;
#pragma unroll
      for (int m2 = 0; m2 < 2; ++m2)
#pragma unroll
        for (int sc = 0; sc < 4; ++sc) {
          iA[m2][sc].v = *(const int4v*)(pAi + sc * 8192 + abase + m2 * 1024);
          iB[m2][sc].v = *(const int4v*)(pBi + sc * 8192 + abase + m2 * 1024);
        }
    }
#pragma unroll
    for (int m2 = 0; m2 < 2; ++m2)
#pragma unroll
      for (int n2 = 0; n2 < 4; ++n2) { accA[m2][n2] = Z4; accB[m2][n2] = Z4; }
  }
#undef STAGE

  // one write per (block, wave): 254*8 slots of 3 doubles
  if (lane == 0) {
    double* sp = scalPart + (size_t)(p * 8 + w) * 3;
    sp[0] = dp0; sp[1] = dp1; sp[2] = dp2;
  }
}

// ---------------------------------------------------------------------------
// Final combine (fp64 to survive the ~4-decade cancellation in S terms).
// ---------------------------------------------------------------------------
__global__ __launch_bounds__(256)
void finalize_kernel(const float* __restrict__ Ra, const float* __restrict__ Rb,
                     const double* __restrict__ scalPart, int NS,
                     const float* __restrict__ coxo,
                     const float* __restrict__ iw, const float* __restrict__ ic,
                     float* __restrict__ out, int B)
{
  const int tid = threadIdx.x;
  double v[8];
#pragma unroll
  for (int k = 0; k < 8; ++k) v[k] = 0.0;
  for (int i = tid; i < B; i += 256) {
    const double a = Ra[i], b = Rb[i];
    v[0] += a; v[1] += b; v[2] += a * b; v[3] += a * a; v[4] += b * b;
  }
  for (int i = tid; i < NS; i += 256) {
    const double* sp = scalPart + (size_t)i * 3;
    v[5] += sp[0]; v[6] += sp[1]; v[7] += sp[2];
  }
#pragma unroll
  for (int k = 0; k < 8; ++k)
#pragma unroll
    for (int off = 32; off; off >>= 1) v[k] += __shfl_xor(v[k], off);
  __shared__ double sred[32];
  const int w = tid >> 6;
  if ((tid & 63) == 0) {
#pragma unroll
    for (int k = 0; k < 8; ++k) sred[k * 4 + w] = v[k];
  }
  __syncthreads();
  if (tid == 0) {
    double r[8];
#pragma unroll
    for (int k = 0; k < 8; ++k) r[k] = sred[k * 4] + sred[k * 4 + 1] + sred[k * 4 + 2] + sred[k * 4 + 3];
    const double ta = r[0], tb = r[1], sab = r[2], saa = r[3], sbb = r[4];
    const double Pab = r[5], Paa = r[6], Pbb = r[7];
    const double n = (double)B;
    const double Sab = Pab - (2.0 / n) * sab + ta * tb / (n * n);
    const double Saa = Paa - (2.0 / n) * saa + ta * ta / (n * n);
    const double Sbb = Pbb - (2.0 / n) * sbb + tb * tb / (n * n);
    const double dcov = Sab / (n * n);
    const double va = Saa / (n * n);
    const double vb = Sbb / (n * n);
    const double l_cca = 1.0 - dcov / sqrt(fmax(va * vb, 1e-8));
    const double total = (double)coxo[0] + (double)coxo[1]
                       + (0.1 * l_cca + 0.05 * ((double)iw[0] + (double)ic[0]));
    out[0] = (float)total;
  }
}

// ---------------------------------------------------------------------------
extern "C" void kernel_launch(void* const* d_in, const int* in_sizes, int n_in,
                              void* d_out, int out_size, void* d_ws, size_t ws_size,
                              hipStream_t stream)
{
  (void)n_in; (void)out_size; (void)ws_size;
  const float* risk_os   = (const float*)d_in[0];
  const float* risk_rfs  = (const float*)d_in[1];
  const float* z_ct      = (const float*)d_in[2];
  const float* z_wsi     = (const float*)d_in[3];
  const float* intra_wsi = (const float*)d_in[4];
  const float* intra_ct  = (const float*)d_in[5];
  const int* evt_os  = (const int*)d_in[6];
  const int* tm_os   = (const int*)d_in[7];
  const int* evt_rfs = (const int*)d_in[8];
  const int* tm_rfs  = (const int*)d_in[9];

  const int B = in_sizes[0];        // 8192
  const int D = in_sizes[2] / B;    // 256
  const int nt = B / 128;           // 64
  const int NS = 254 * 8;           // per-(block,wave) scalar slots

  // ws layout (float units):
  // Ra | Rb | coxo(16) | na | nb | scalPart (NS*3 doubles) | fp8 packed z
  float* ws = (float*)d_ws;
  float* Ra = ws;
  float* Rb = ws + B;
  float* coxo = ws + 2 * B;
  float* na  = ws + 2 * B + 16;
  float* nbv = ws + 3 * B + 16;
  double* scalPart = (double*)(ws + 4 * B + 16);
  unsigned char* zpa = (unsigned char*)(ws + 4 * B + 16 + 6 * NS + 8);
  unsigned char* zpb = zpa + (size_t)B * D;

  prep_kernel<<<(2 * B) / 4, 256, 0, stream>>>(z_ct, z_wsi, na, nbv, zpa, zpb, Ra, Rb, B, D);
  dcor_kernel<<<256, 512, 0, stream>>>(zpa, zpb, na, nbv, Ra, Rb, scalPart,
                                       risk_os, evt_os, tm_os, risk_rfs, evt_rfs, tm_rfs,
                                       coxo, nt, B, D);
  finalize_kernel<<<1, 256, 0, stream>>>(Ra, Rb, scalPart, NS, coxo, intra_wsi, intra_ct, (float*)d_out, B);
}